// Round 10
// baseline (53.018 us; speedup 1.0000x reference)
//
#include <hip/hip_runtime.h>
#include <stdint.h>

// Problem constants (fixed by the reference: B=2048, K=6144, MU=2,
// G0 = 1 + D^2 (feedback), G1 = 1 + D + D^2 (parity)).
#define KLEN  6144
#define BROWS 2048
#define NG    (BROWS / 32)      // 64 bit-groups of 32 rows
#define GK    (NG * KLEN)       // u32 words per packed plane = 393216
#define NT    256               // threads per block (pack/emit)

// scan: 512-thread blocks, thread-chunk CL2=12 (EVEN — required so M^CL == I)
#define NT2   512
#define CL2   (KLEN / NT2)      // 12

// emit tiling: block = (g, tile); all 32 rows emitted per block (planes staged ONCE)
#define ET    768
#define NTILE (KLEN / ET)       // 8
#define EMIT_GRID (NG * NTILE)  // 512 = exactly 2 blocks/CU
#define QROW  (3 * ET / 4)      // 576 float4-quads per row per tile
#define QPB   (32 * QROW)       // 18432 quads per block

typedef float vfloat4 __attribute__((ext_vector_type(4)));  // native vec for nt ops

// RSC recursion (bitwise over 32 rows packed in a u32):
//   fb = u ^ s1;  par = u ^ s0;  (s0,s1) <- (fb, s0)
// State map's linear part M satisfies M^2 = I, so for even-length chunks the
// actual chunk init = XOR of preceding chunks' zero-init end states.
//
// Round-6 post-mortem: cooperative grid.sync() ~190 us/barrier here — keep
// three plain dispatches (kernel boundary ~2 us in the captured graph).
// Round-9 post-mortem: emit's NRS=4 row-octet split staged each plane tile
// 4x (~75 MB of fetch vs 19 MB minimum) — this round removes the redundancy.

// ---------------------------------------------------------------------------
// Kernel A: bit-pack bits[B][K] -> packedS[g*K + t] (bit j = row g*32+j).
// Thread = (g, quad-of-t): 32 plain float4 loads (measured-ceiling path),
// one uint4 store.
__global__ __launch_bounds__(NT) void pack_kernel(const float* __restrict__ bits,
                                                  uint32_t* __restrict__ packedS) {
    int task = blockIdx.x * NT + threadIdx.x;    // [0, GK/4)
    int g  = task / (KLEN / 4);
    int tq = task - g * (KLEN / 4);
    const float* rb = bits + (size_t)g * 32 * KLEN + 4 * tq;
    uint32_t w0 = 0, w1 = 0, w2 = 0, w3 = 0;
#pragma unroll 1
    for (int j0 = 0; j0 < 32; j0 += 8) {
#pragma unroll
        for (int j = 0; j < 8; ++j) {
            float4 f = *(const float4*)(rb + (size_t)(j0 + j) * KLEN);
            w0 |= (f.x > 0.5f ? 1u : 0u) << (j0 + j);
            w1 |= (f.y > 0.5f ? 1u : 0u) << (j0 + j);
            w2 |= (f.z > 0.5f ? 1u : 0u) << (j0 + j);
            w3 |= (f.w > 0.5f ? 1u : 0u) << (j0 + j);
        }
    }
    *(uint4*)(packedS + g * KLEN + 4 * tq) = make_uint4(w0, w1, w2, w3);
}

// ---------------------------------------------------------------------------
// Kernel B: fused parallel scan. Block = (enc, g), 512 threads; thread c owns
// chunk c (CL2=12 steps). Zero-init scan -> end states; block-wide XOR prefix
// (Hillis-Steele in LDS, 9 rounds); rescan from corrected init using
// register-cached u[], emit packed parities as aligned uint4 stores.
__global__ __launch_bounds__(NT2) void scan_kernel(const uint32_t* __restrict__ packedS,
                                                   const int* __restrict__ perm,
                                                   uint32_t* __restrict__ p1,
                                                   uint32_t* __restrict__ p2) {
    __shared__ uint32_t a0[NT2], a1[NT2];
    int c   = threadIdx.x;
    int enc = blockIdx.x >> 6;        // 0 or 1
    int g   = blockIdx.x & (NG - 1);
    const uint32_t* base = packedS + g * KLEN;
    int t0 = c * CL2;

    uint32_t u[CL2];
    if (enc) {
#pragma unroll
        for (int i = 0; i < CL2; ++i) u[i] = base[perm[t0 + i]];
    } else {
#pragma unroll
        for (int i = 0; i < CL2; ++i) u[i] = base[t0 + i];
    }

    // zero-init chunk scan -> end state
    uint32_t s0 = 0, s1 = 0;
#pragma unroll
    for (int i = 0; i < CL2; ++i) { uint32_t n0 = u[i] ^ s1; s1 = s0; s0 = n0; }

    // block-wide XOR prefix (Hillis-Steele), then exclusive
    a0[c] = s0; a1[c] = s1;
    __syncthreads();
#pragma unroll
    for (int off = 1; off < NT2; off <<= 1) {
        uint32_t x0 = 0, x1 = 0;
        if (c >= off) { x0 = a0[c - off]; x1 = a1[c - off]; }
        __syncthreads();
        a0[c] ^= x0; a1[c] ^= x1;
        __syncthreads();
    }
    s0 = c ? a0[c - 1] : 0u;
    s1 = c ? a1[c - 1] : 0u;

    // rescan with actual init, emit packed parities (uint4 every 4 steps)
    uint32_t* __restrict__ pout = enc ? p2 : p1;
    uint32_t pq0, pq1, pq2;
#pragma unroll
    for (int i = 0; i < CL2; ++i) {
        uint32_t pv = u[i] ^ s0;
        uint32_t n0 = u[i] ^ s1; s1 = s0; s0 = n0;
        if ((i & 3) == 0) pq0 = pv;
        else if ((i & 3) == 1) pq1 = pv;
        else if ((i & 3) == 2) pq2 = pv;
        else *(uint4*)(pout + g * KLEN + t0 + i - 3) = make_uint4(pq0, pq1, pq2, pv);
    }
}

// ---------------------------------------------------------------------------
// Kernel C: emit codeword [sys, p1, p2] interleaved. Block = (g, tile):
// stage 3 x ET plane words in LDS ONCE (uint4-coalesced, 9 KB), then emit all
// 32 rows x 576 quads. Stores: wave-contiguous 1 KB nontemporal float4.
__global__ __launch_bounds__(NT) void emit_kernel(const uint32_t* __restrict__ ps,
                                                  const uint32_t* __restrict__ p1,
                                                  const uint32_t* __restrict__ p2,
                                                  float* __restrict__ out) {
    __shared__ uint32_t l0[ET], l1[ET], l2[ET];
    int blk  = blockIdx.x;
    int g    = blk / NTILE;
    int tile = blk - g * NTILE;
    int i    = threadIdx.x;

    size_t pbase = (size_t)g * KLEN + (size_t)tile * ET;
    if (i < ET / 4) {   // 192 threads stage 3 x 192 uint4
        *(uint4*)(l0 + 4 * i) = *(const uint4*)(ps + pbase + 4 * i);
        *(uint4*)(l1 + 4 * i) = *(const uint4*)(p1 + pbase + 4 * i);
        *(uint4*)(l2 + 4 * i) = *(const uint4*)(p2 + pbase + 4 * i);
    }
    __syncthreads();

    float* gout = out + (size_t)(g * 32) * (3 * KLEN) + (size_t)tile * (3 * ET);
#pragma unroll 2
    for (int k = 0; k < QPB / NT; ++k) {            // 72 iterations
        int idx  = k * NT + i;                      // [0, 18432)
        int row  = idx / QROW;                      // const-div (magic mul)
        int qq   = idx - row * QROW;                // quad within row-tile
        int pos0 = 4 * qq;                          // [0, 2304)
        int t0   = pos0 / 3;                        // const-div
        int r0   = pos0 - 3 * t0;
        uint32_t w00 = l0[t0],     w01 = l1[t0],     w02 = l2[t0];
        uint32_t w10 = l0[t0 + 1], w11 = l1[t0 + 1], w12 = l2[t0 + 1];
        // element s: pos=pos0+s, comp=(pos0+s)%3 (0=sys,1=p1,2=p2)
        uint32_t e0 = r0 == 0 ? w00 : (r0 == 1 ? w01 : w02);
        uint32_t e1 = r0 == 0 ? w01 : (r0 == 1 ? w02 : w10);
        uint32_t e2 = r0 == 0 ? w02 : (r0 == 1 ? w10 : w11);
        uint32_t e3 = r0 == 0 ? w10 : (r0 == 1 ? w11 : w12);
        int bit = row;                              // row within group = shift
        vfloat4 f;
        f.x = (float)((e0 >> bit) & 1u);
        f.y = (float)((e1 >> bit) & 1u);
        f.z = (float)((e2 >> bit) & 1u);
        f.w = (float)((e3 >> bit) & 1u);
        __builtin_nontemporal_store(f,
            (vfloat4*)(gout + (size_t)row * (3 * KLEN) + pos0));
    }
}

// ---------------------------------------------------------------------------
extern "C" void kernel_launch(void* const* d_in, const int* in_sizes, int n_in,
                              void* d_out, int out_size, void* d_ws, size_t ws_size,
                              hipStream_t stream) {
    const float* bits = (const float*)d_in[0];   // [B*K] float 0/1
    const int*   perm = (const int*)d_in[1];     // [K] int32
    float* out = (float*)d_out;                  // [B * 3K] float

    uint32_t* ws = (uint32_t*)d_ws;
    uint32_t* packedS = ws;                      // [GK]
    uint32_t* p1      = ws + (size_t)GK;         // [GK]
    uint32_t* p2      = ws + (size_t)2 * GK;     // [GK]

    hipLaunchKernelGGL(pack_kernel, dim3(GK / 4 / NT), dim3(NT), 0, stream,
                       bits, packedS);
    hipLaunchKernelGGL(scan_kernel, dim3(2 * NG), dim3(NT2), 0, stream,
                       packedS, perm, p1, p2);
    hipLaunchKernelGGL(emit_kernel, dim3(EMIT_GRID), dim3(NT), 0, stream,
                       packedS, p1, p2, out);
}